// Round 8
// baseline (66.789 us; speedup 1.0000x reference)
//
#include <hip/hip_runtime.h>

// Problem constants (from reference)
#define NB 4
#define NN 20000
#define NE 320000
#define HH 128

#define HBLK 32     // histogram blocks (each holds a full 80 KB LDS histogram)
#define HTHR 1024   // threads per histogram block
#define CHUNKS 128  // node chunks for the weighted-sum kernel
#define WTHR 512    // threads per wsum block (16 node-groups x 32 lanes)
#define PER ((NN + CHUNKS - 1) / CHUNKS)   // 157 nodes per wsum chunk

// ws layout (floats):
//   pdeg   [HBLK][NN]          per-block degree partials
//   dinv   [NN]                rsqrt(deg+1)
//   ps     [HBLK][NN]          per-block s partials
//   partial[CHUNKS][NB][HH]    wsum partials
#define OFF_PDEG    0
#define OFF_DINV    (HBLK * NN)
#define OFF_PS      (OFF_DINV + NN)
#define OFF_PARTIAL (OFF_PS + HBLK * NN)

// --- K1: per-block LDS degree histogram (NO global atomics) ---
__global__ void __launch_bounds__(HTHR) deg_hist_kernel(
        const int* __restrict__ dst, float* __restrict__ pdeg) {
    __shared__ float hist[NN];   // 80 KB
    const int t = threadIdx.x, bk = blockIdx.x;
    for (int i = t; i < NN; i += HTHR) hist[i] = 0.0f;
    __syncthreads();
    for (int e = bk * HTHR + t; e < NE; e += HBLK * HTHR)
        atomicAdd(&hist[dst[e]], 1.0f);          // LDS atomic (ds_add_f32)
    __syncthreads();
    float* out = pdeg + (size_t)bk * NN;
    for (int i = t; i < NN; i += HTHR) out[i] = hist[i];  // coalesced dump
}

// --- K2: dinv[n] = rsqrt(1 + sum_c pdeg[c][n]) ---
__global__ void reduce_deg_kernel(const float* __restrict__ pdeg,
                                  float* __restrict__ dinv) {
    const int n = blockIdx.x * 256 + threadIdx.x;
    if (n >= NN) return;
    float acc = 1.0f;  // self-loop
    #pragma unroll 8
    for (int c = 0; c < HBLK; ++c) acc += pdeg[(size_t)c * NN + n];
    dinv[n] = rsqrtf(acc);
}

// --- K3: per-block LDS s histogram: s[src] += dinv[dst] ---
__global__ void __launch_bounds__(HTHR) s_hist_kernel(
        const int* __restrict__ src, const int* __restrict__ dst,
        const float* __restrict__ dinv, float* __restrict__ ps) {
    __shared__ float hist[NN];   // 80 KB
    const int t = threadIdx.x, bk = blockIdx.x;
    for (int i = t; i < NN; i += HTHR) hist[i] = 0.0f;
    __syncthreads();
    for (int e = bk * HTHR + t; e < NE; e += HBLK * HTHR)
        atomicAdd(&hist[src[e]], dinv[dst[e]]);  // L2/L3 gather + LDS atomic
    __syncthreads();
    float* out = ps + (size_t)bk * NN;
    for (int i = t; i < NN; i += HTHR) out[i] = hist[i];
}

// --- K4: weighted feature sum (w computed inline from ps+dinv) ---
// grid (CHUNKS, NB), 512 threads = 16 node-groups x 32 lanes.
// q<16 lanes cover feat_a[n, q*4..q*4+3], q>=16 cover feat_b.
__global__ void __launch_bounds__(WTHR) wsum_kernel(
        const float* __restrict__ fa, const float* __restrict__ fb,
        const float* __restrict__ dinv, const float* __restrict__ ps,
        float* __restrict__ partial) {
    __shared__ float wl[PER];
    __shared__ float4 smem[WTHR];
    const int t = threadIdx.x;
    const int c = blockIdx.x, b = blockIdx.y;
    const int n0 = c * PER;
    const int n1 = min(NN, n0 + PER);
    const int cnt = n1 - n0;

    // w[n] = dinv[n]*(dinv[n] + sum_c ps[c][n]) for this chunk's nodes
    for (int i = t; i < cnt; i += WTHR) {
        const int n = n0 + i;
        float acc = 0.0f;
        #pragma unroll 8
        for (int cc = 0; cc < HBLK; ++cc) acc += ps[(size_t)cc * NN + n];
        const float di = dinv[n];
        wl[i] = di * (di + acc);
    }
    __syncthreads();

    const int g = t >> 5;        // node subgroup 0..15
    const int q = t & 31;
    const float* base = (q < 16)
        ? (fa + (size_t)b * NN * 64 + (size_t)q * 4)
        : (fb + (size_t)b * NN * 64 + (size_t)(q - 16) * 4);

    float4 acc = make_float4(0.f, 0.f, 0.f, 0.f);
    for (int n = n0 + g; n < n1; n += 16) {
        float wn = wl[n - n0];
        float4 x = *reinterpret_cast<const float4*>(base + (size_t)n * 64);
        acc.x += wn * x.x; acc.y += wn * x.y; acc.z += wn * x.z; acc.w += wn * x.w;
    }

    smem[t] = acc;
    __syncthreads();
    if (t < 32) {
        float4 r = smem[t];
        #pragma unroll
        for (int gg = 1; gg < 16; ++gg) {
            float4 o = smem[gg * 32 + t];
            r.x += o.x; r.y += o.y; r.z += o.z; r.w += o.w;
        }
        const int k = (t < 16) ? t * 4 : 64 + (t - 16) * 4;
        float* p = partial + ((size_t)c * NB + b) * HH + k;
        p[0] = r.x; p[1] = r.y; p[2] = r.z; p[3] = r.w;
    }
}

// --- K5: reduce partials + MLP head. One block, B*H = 512 threads. ---
// Thread t owns (b = t>>7, k = t&127).
__global__ void __launch_bounds__(NB * HH) mlp_kernel(
        const float* __restrict__ partial,
        const float* __restrict__ Wg, const float* __restrict__ bg,
        const float* __restrict__ W1, const float* __restrict__ b1,
        const float* __restrict__ W2, const float* __restrict__ b2,
        float* __restrict__ out) {
    __shared__ float xs[NB][HH];
    __shared__ float ys[NB][HH];
    __shared__ float red[NB][HH];
    const int t = threadIdx.x;
    const int bb = t >> 7;           // 0..3
    const int kk = t & (HH - 1);     // 0..127

    float vsum = 0.0f;
    #pragma unroll 8
    for (int cc = 0; cc < CHUNKS; ++cc)
        vsum += partial[((size_t)cc * NB + bb) * HH + kk];
    xs[bb][kk] = vsum * (1.0f / NN);
    __syncthreads();

    // layer 1: pooled = xs @ Wg + bg
    float a1 = bg[kk];
    #pragma unroll 8
    for (int j = 0; j < HH; ++j) a1 += xs[bb][j] * Wg[j * HH + kk];
    ys[bb][kk] = a1;
    __syncthreads();

    // layer 2: hid = relu(ys @ W1 + b1), fold W2 scale
    float a2 = b1[kk];
    #pragma unroll 8
    for (int j = 0; j < HH; ++j) a2 += ys[bb][j] * W1[j * HH + kk];
    a2 = fmaxf(a2, 0.0f);
    red[bb][kk] = a2 * W2[kk];
    __syncthreads();

    // tree-reduce 128 -> 1 per batch
    #pragma unroll
    for (int off = HH / 2; off > 0; off >>= 1) {
        if (kk < off) red[bb][kk] += red[bb][kk + off];
        __syncthreads();
    }
    if (kk == 0) out[bb] = red[bb][0] + b2[0];
}

extern "C" void kernel_launch(void* const* d_in, const int* in_sizes, int n_in,
                              void* d_out, int out_size, void* d_ws, size_t ws_size,
                              hipStream_t stream) {
    const float* fa = (const float*)d_in[0];   // [B,N,64]
    const float* fb = (const float*)d_in[1];   // [B,N,64]
    const int*   ei = (const int*)d_in[2];     // [2,E]
    const float* Wg = (const float*)d_in[3];   // [H,H]
    const float* bg = (const float*)d_in[4];   // [H]
    const float* W1 = (const float*)d_in[5];   // [H,H]
    const float* b1 = (const float*)d_in[6];   // [H]
    const float* W2 = (const float*)d_in[7];   // [H,1]
    const float* b2 = (const float*)d_in[8];   // [1]
    float* out = (float*)d_out;

    const int* src = ei;
    const int* dst = ei + NE;

    float* ws   = (float*)d_ws;
    float* pdeg = ws + OFF_PDEG;
    float* dinv = ws + OFF_DINV;
    float* ps   = ws + OFF_PS;
    float* prt  = ws + OFF_PARTIAL;

    deg_hist_kernel<<<HBLK, HTHR, 0, stream>>>(dst, pdeg);

    const int rb = (NN + 255) / 256;
    reduce_deg_kernel<<<rb, 256, 0, stream>>>(pdeg, dinv);

    s_hist_kernel<<<HBLK, HTHR, 0, stream>>>(src, dst, dinv, ps);

    dim3 grid(CHUNKS, NB);
    wsum_kernel<<<grid, WTHR, 0, stream>>>(fa, fb, dinv, ps, prt);

    mlp_kernel<<<1, NB * HH, 0, stream>>>(prt, Wg, bg, W1, b1, W2, b2, out);
}

// Round 9
// 62.923 us; speedup vs baseline: 1.0614x; 1.0614x over previous
//
#include <hip/hip_runtime.h>

// Problem constants (from reference)
#define NB 4
#define NN 20000
#define NE 320000
#define HH 128

#define EBLK 64     // histogram blocks (each holds a full 80 KB LDS histogram)
#define HTHR 1024   // threads per histogram block
#define CHUNKS 128  // node chunks for the weighted-sum kernel
#define WTHR 512    // threads per wsum block (16 node-groups x 32 lanes)
#define PER ((NN + CHUNKS - 1) / CHUNKS)   // 157 nodes per wsum chunk
#define TOTW (CHUNKS * NB)                 // 512 wsum blocks

// ws layout (floats):
//   pdeg   [EBLK][NN]   per-block degree partials
//   dinv   [NN]         rsqrt(deg+1)
//   ps     [EBLK][NN]   per-block s partials
//   v      [NB*HH]      pooled feature sums (atomic accum)
//   counter(1 int)      completion counter for last-block MLP
#define OFF_PDEG 0
#define OFF_DINV (EBLK * NN)
#define OFF_PS   (OFF_DINV + NN)
#define OFF_V    (OFF_PS + EBLK * NN)
#define OFF_CNT  (OFF_V + NB * HH)

// --- K1: per-block LDS degree histogram (NO global atomics) ---
__global__ void __launch_bounds__(HTHR) deg_hist_kernel(
        const int* __restrict__ dst, float* __restrict__ pdeg) {
    __shared__ float hist[NN];   // 80 KB
    const int t = threadIdx.x, bk = blockIdx.x;
    for (int i = t; i < NN; i += HTHR) hist[i] = 0.0f;
    __syncthreads();
    for (int e = bk * HTHR + t; e < NE; e += EBLK * HTHR)
        atomicAdd(&hist[dst[e]], 1.0f);          // LDS atomic (ds_add_f32)
    __syncthreads();
    float* out = pdeg + (size_t)bk * NN;
    for (int i = t; i < NN; i += HTHR) out[i] = hist[i];  // coalesced dump
}

// --- K2: dinv[n] = rsqrt(1 + sum_c pdeg[c][n]); block 0 zeroes v+counter ---
__global__ void reduce_deg_kernel(const float* __restrict__ pdeg,
                                  float* __restrict__ dinv,
                                  float* __restrict__ v, int* __restrict__ counter) {
    if (blockIdx.x == 0) {
        v[threadIdx.x] = 0.0f;
        v[threadIdx.x + 256] = 0.0f;
        if (threadIdx.x == 0) *counter = 0;
    }
    const int n = blockIdx.x * 256 + threadIdx.x;
    if (n >= NN) return;
    float acc = 1.0f;  // self-loop
    #pragma unroll 8
    for (int c = 0; c < EBLK; ++c) acc += pdeg[(size_t)c * NN + n];
    dinv[n] = rsqrtf(acc);
}

// --- K3: per-block LDS s histogram: s[src] += dinv[dst] ---
__global__ void __launch_bounds__(HTHR) s_hist_kernel(
        const int* __restrict__ src, const int* __restrict__ dst,
        const float* __restrict__ dinv, float* __restrict__ ps) {
    __shared__ float hist[NN];   // 80 KB
    const int t = threadIdx.x, bk = blockIdx.x;
    for (int i = t; i < NN; i += HTHR) hist[i] = 0.0f;
    __syncthreads();
    for (int e = bk * HTHR + t; e < NE; e += EBLK * HTHR)
        atomicAdd(&hist[src[e]], dinv[dst[e]]);  // L2 gather + LDS atomic
    __syncthreads();
    float* out = ps + (size_t)bk * NN;
    for (int i = t; i < NN; i += HTHR) out[i] = hist[i];
}

// --- K4: weighted feature sum + fence-free last-block MLP ---
// grid (CHUNKS, NB), 512 threads = 16 node-groups x 32 lanes.
// v is accumulated with device-scope atomicAdd (coherent point), each block's
// v-atomics are ordered before its counter-increment by a wave-local
// s_waitcnt vmcnt(0) (wave 0 issued all of them), and the last block reads v
// back with atomicAdd(p, 0.0f) -- no __threadfence / L2 writeback anywhere.
__global__ void __launch_bounds__(WTHR) wsum_mlp_kernel(
        const float* __restrict__ fa, const float* __restrict__ fb,
        const float* __restrict__ dinv, const float* __restrict__ ps,
        const float* __restrict__ Wg, const float* __restrict__ bg,
        const float* __restrict__ W1, const float* __restrict__ b1,
        const float* __restrict__ W2, const float* __restrict__ b2,
        float* __restrict__ v, int* __restrict__ counter,
        float* __restrict__ out) {
    __shared__ float wl[PER];
    __shared__ float4 smem[WTHR];
    __shared__ int lastflag;
    const int t = threadIdx.x;
    const int c = blockIdx.x, b = blockIdx.y;
    const int n0 = c * PER;
    const int n1 = min(NN, n0 + PER);
    const int cnt = n1 - n0;

    // w[n] = dinv[n]*(dinv[n] + sum_c ps[c][n]) for this chunk's nodes
    for (int i = t; i < cnt; i += WTHR) {
        const int n = n0 + i;
        float acc = 0.0f;
        #pragma unroll 8
        for (int cc = 0; cc < EBLK; ++cc) acc += ps[(size_t)cc * NN + n];
        const float di = dinv[n];
        wl[i] = di * (di + acc);
    }
    __syncthreads();

    const int g = t >> 5;        // node subgroup 0..15
    const int q = t & 31;
    const float* base = (q < 16)
        ? (fa + (size_t)b * NN * 64 + (size_t)q * 4)
        : (fb + (size_t)b * NN * 64 + (size_t)(q - 16) * 4);

    float4 acc = make_float4(0.f, 0.f, 0.f, 0.f);
    for (int n = n0 + g; n < n1; n += 16) {
        float wn = wl[n - n0];
        float4 x = *reinterpret_cast<const float4*>(base + (size_t)n * 64);
        acc.x += wn * x.x; acc.y += wn * x.y; acc.z += wn * x.z; acc.w += wn * x.w;
    }

    smem[t] = acc;
    __syncthreads();
    if (t < 32) {   // all of wave 0: issues ALL of this block's v-atomics
        float4 r = smem[t];
        #pragma unroll
        for (int gg = 1; gg < 16; ++gg) {
            float4 o = smem[gg * 32 + t];
            r.x += o.x; r.y += o.y; r.z += o.z; r.w += o.w;
        }
        const int k = (t < 16) ? t * 4 : 64 + (t - 16) * 4;
        float* vb = v + b * HH + k;
        atomicAdd(vb + 0, r.x);
        atomicAdd(vb + 1, r.y);
        atomicAdd(vb + 2, r.z);
        atomicAdd(vb + 3, r.w);
    }
    if (t == 0) {
        // wave 0 waits for its own v-atomics to reach the coherent point,
        // then publishes completion. No cache flush needed.
        asm volatile("s_waitcnt vmcnt(0)" ::: "memory");
        int old = atomicAdd(counter, 1);
        lastflag = (old == TOTW - 1);
    }
    __syncthreads();
    if (!lastflag) return;

    // ---- last block: read v coherently and run the MLP head ----
    __shared__ float xs[NB][HH];
    __shared__ float ys[NB][HH];
    __shared__ float red[NB][HH];
    const int bb = t >> 7;           // 0..3
    const int kk = t & (HH - 1);     // 0..127

    float val = atomicAdd(&v[t], 0.0f);   // coherent RMW read of v[bb*HH+kk]
    xs[bb][kk] = val * (1.0f / NN);
    __syncthreads();

    // layer 1: pooled = xs @ Wg + bg
    float a1 = bg[kk];
    #pragma unroll 8
    for (int j = 0; j < HH; ++j) a1 += xs[bb][j] * Wg[j * HH + kk];
    ys[bb][kk] = a1;
    __syncthreads();

    // layer 2: hid = relu(ys @ W1 + b1), fold W2 scale
    float a2 = b1[kk];
    #pragma unroll 8
    for (int j = 0; j < HH; ++j) a2 += ys[bb][j] * W1[j * HH + kk];
    a2 = fmaxf(a2, 0.0f);
    red[bb][kk] = a2 * W2[kk];
    __syncthreads();

    // tree-reduce 128 -> 1 per batch
    #pragma unroll
    for (int off = HH / 2; off > 0; off >>= 1) {
        if (kk < off) red[bb][kk] += red[bb][kk + off];
        __syncthreads();
    }
    if (kk == 0) out[bb] = red[bb][0] + b2[0];
}

extern "C" void kernel_launch(void* const* d_in, const int* in_sizes, int n_in,
                              void* d_out, int out_size, void* d_ws, size_t ws_size,
                              hipStream_t stream) {
    const float* fa = (const float*)d_in[0];   // [B,N,64]
    const float* fb = (const float*)d_in[1];   // [B,N,64]
    const int*   ei = (const int*)d_in[2];     // [2,E]
    const float* Wg = (const float*)d_in[3];   // [H,H]
    const float* bg = (const float*)d_in[4];   // [H]
    const float* W1 = (const float*)d_in[5];   // [H,H]
    const float* b1 = (const float*)d_in[6];   // [H]
    const float* W2 = (const float*)d_in[7];   // [H,1]
    const float* b2 = (const float*)d_in[8];   // [1]
    float* out = (float*)d_out;

    const int* src = ei;
    const int* dst = ei + NE;

    float* ws   = (float*)d_ws;
    float* pdeg = ws + OFF_PDEG;
    float* dinv = ws + OFF_DINV;
    float* ps   = ws + OFF_PS;
    float* v    = ws + OFF_V;
    int* counter = (int*)(ws + OFF_CNT);

    deg_hist_kernel<<<EBLK, HTHR, 0, stream>>>(dst, pdeg);

    const int rb = (NN + 255) / 256;
    reduce_deg_kernel<<<rb, 256, 0, stream>>>(pdeg, dinv, v, counter);

    s_hist_kernel<<<EBLK, HTHR, 0, stream>>>(src, dst, dinv, ps);

    dim3 grid(CHUNKS, NB);
    wsum_mlp_kernel<<<grid, WTHR, 0, stream>>>(fa, fb, dinv, ps,
                                               Wg, bg, W1, b1, W2, b2,
                                               v, counter, out);
}